// Round 10
// baseline (41.040 us; speedup 1.0000x reference)
//
#include <hip/hip_runtime.h>
#include <hip/hip_bf16.h>

#define T 32
#define WAYS 64
#define SHOTS 8
#define CDIM 1024
#define WQ 1024
#define BK 128
#define NK 8    // K-steps of 128

typedef float f32x4 __attribute__((ext_vector_type(4)));
typedef __bf16 bf16x8 __attribute__((ext_vector_type(8)));

// Single fused kernel, NO fences, NO release/acquire cache maintenance.
// Grid = 512 = 2 blocks/CU exactly (all co-resident; 64.5KB LDS, VGPR<128).
// XCD-chunked vb: the 16 blocks of episode t (producers AND consumers of its
// 64 protos) share one XCD -> its L2 is the coherence point. Producer stores
// drain to L2 at __syncthreads (compiler emits vmcnt(0) before s_barrier);
// a RELAXED agent add publishes; consumers RELAXED-poll a 128B-padded
// per-episode flag; proto first-reads are L1-cold -> hit L2 -> fresh data.
__global__ __launch_bounds__(512, 4) void fused_kernel(const float* __restrict__ query,
                                                       const float* __restrict__ support,
                                                       float* __restrict__ out,
                                                       __bf16* __restrict__ proto,
                                                       float* __restrict__ p_sq,
                                                       int* __restrict__ cnt) {
    const int bx = blockIdx.x;
    const int vb = (bx & 7) * 64 + (bx >> 3);   // XCD-chunked virtual block id
    const int t   = vb >> 4;
    const int mt  = vb & 15;
    const int tid = threadIdx.x;
    const int lane = tid & 63;
    const int wid  = tid >> 6;

    __shared__ float redA[8];

    // ================= Phase A: this block's 4 protos + p_sq =================
    {
        const int bid = vb * 4 + (wid >> 1);        // = t*64 + mt*4 + (0..3)
        const int ch  = (wid & 1) * 512;            // channel half
        const float* sp = support + (size_t)bid * (SHOTS * CDIM) + ch;

        f32x4 a0 = (f32x4){0.f, 0.f, 0.f, 0.f};
        f32x4 a1 = (f32x4){0.f, 0.f, 0.f, 0.f};
#pragma unroll
        for (int s = 0; s < SHOTS; ++s) {
            a0 += *reinterpret_cast<const f32x4*>(sp + s * CDIM + lane * 4);
            a1 += *reinterpret_cast<const f32x4*>(sp + s * CDIM + 256 + lane * 4);
        }
        a0 *= 0.125f; a1 *= 0.125f;
        float ps = a0.x * a0.x + a0.y * a0.y + a0.z * a0.z + a0.w * a0.w +
                   a1.x * a1.x + a1.y * a1.y + a1.z * a1.z + a1.w * a1.w;

        union { __bf16 h[4]; uint2 u; } q0, q1;
        q0.h[0] = (__bf16)a0.x; q0.h[1] = (__bf16)a0.y;
        q0.h[2] = (__bf16)a0.z; q0.h[3] = (__bf16)a0.w;
        q1.h[0] = (__bf16)a1.x; q1.h[1] = (__bf16)a1.y;
        q1.h[2] = (__bf16)a1.z; q1.h[3] = (__bf16)a1.w;
        __bf16* pb = proto + (size_t)bid * CDIM + ch;
        *reinterpret_cast<uint2*>(pb + lane * 4)       = q0.u;
        *reinterpret_cast<uint2*>(pb + 256 + lane * 4) = q1.u;

#pragma unroll
        for (int m = 1; m <= 32; m <<= 1) ps += __shfl_xor(ps, m, 64);
        if (lane == 0) redA[wid] = ps;
        __syncthreads();
        if (tid < 4) p_sq[vb * 4 + tid] = redA[2 * tid] + redA[2 * tid + 1];
        __syncthreads();   // compiler emits vmcnt(0) before s_barrier: all
                           // proto/p_sq stores of this block are in L2 now
    }

    // publish: RELAXED add (no wbl2, no fence) on a 128B-padded flag
    if (tid == 0)
        __hip_atomic_fetch_add(&cnt[t * 32], 1, __ATOMIC_RELAXED, __HIP_MEMORY_SCOPE_AGENT);

    // ================= Phase B setup =================
    const int wr = wid >> 1;      // 0..3 : row group of 16
    const int wn = wid & 1;       // 0..1 : way half of 32
    const int fr = lane & 15;
    const int kg = lane >> 4;

    __shared__ __bf16 As[2][64 * BK];
    __shared__ __bf16 Bs[2][64 * BK];
    __shared__ float qsq_s[64];

    const int srow = tid >> 3;
    const int sk8  = tid & 7;

    const float*  qbase = query + ((size_t)(t * WQ + mt * 64 + srow)) * CDIM;
    const __bf16* pbase = proto + ((size_t)(t * WAYS + srow)) * CDIM + sk8 * 16;

    struct StageA { f32x4 a[4]; };
    struct StageB { uint4 b[2]; };

    auto LOADA = [&](int ks) -> StageA {
        StageA s;
        const float* ap = qbase + ks * BK;
#pragma unroll
        for (int p = 0; p < 4; ++p)   // one contiguous 128B line per row
            s.a[p] = *reinterpret_cast<const f32x4*>(ap + p * 32 + sk8 * 4);
        return s;
    };
    auto LOADB = [&](int ks) -> StageB {
        StageB s;
        const __bf16* bp = pbase + ks * BK;
        s.b[0] = *reinterpret_cast<const uint4*>(bp);
        s.b[1] = *reinterpret_cast<const uint4*>(bp + 8);
        return s;
    };

    float qsq = 0.f;

    auto WRITE = [&](int buf, const StageA& sa, const StageB& sb) {
        const int swz = (srow & 7) << 4;
        char* ab = reinterpret_cast<char*>(As[buf]);
#pragma unroll
        for (int p = 0; p < 4; ++p) {
            qsq += sa.a[p].x * sa.a[p].x + sa.a[p].y * sa.a[p].y +
                   sa.a[p].z * sa.a[p].z + sa.a[p].w * sa.a[p].w;
            union { __bf16 h[4]; uint2 u; } pk;
            pk.h[0] = (__bf16)sa.a[p].x; pk.h[1] = (__bf16)sa.a[p].y;
            pk.h[2] = (__bf16)sa.a[p].z; pk.h[3] = (__bf16)sa.a[p].w;
            // thread holds k = p*32 + sk8*4 + {0..3}  ->  row byte 2k
            *reinterpret_cast<uint2*>(ab + ((srow * 256 + p * 64 + sk8 * 8) ^ swz)) = pk.u;
        }
        char* bb = reinterpret_cast<char*>(Bs[buf]);
        *reinterpret_cast<uint4*>(bb + ((srow * 256 + sk8 * 32) ^ swz))      = sb.b[0];
        *reinterpret_cast<uint4*>(bb + ((srow * 256 + sk8 * 32 + 16) ^ swz)) = sb.b[1];
    };

    f32x4 acc[2];
    acc[0] = (f32x4){0.f, 0.f, 0.f, 0.f};
    acc[1] = (f32x4){0.f, 0.f, 0.f, 0.f};

    auto COMPUTE = [&](int buf) {
        const char* ab = reinterpret_cast<const char*>(As[buf]);
        const char* bb = reinterpret_cast<const char*>(Bs[buf]);
#pragma unroll
        for (int ksub = 0; ksub < 4; ++ksub) {
            const int arow = wr * 16 + fr;
            const bf16x8 af = *reinterpret_cast<const bf16x8*>(
                ab + ((arow * 256 + ksub * 64 + kg * 16) ^ ((arow & 7) << 4)));
#pragma unroll
            for (int nf = 0; nf < 2; ++nf) {
                const int way = wn * 32 + nf * 16 + fr;
                const bf16x8 bf = *reinterpret_cast<const bf16x8*>(
                    bb + ((way * 256 + ksub * 64 + kg * 16) ^ ((way & 7) << 4)));
                acc[nf] = __builtin_amdgcn_mfma_f32_16x16x32_bf16(af, bf, acc[nf], 0, 0, 0);
            }
        }
    };

    // issue query loads for tiles 0,1 BEFORE the spin (independent of proto;
    // HBM latency overlaps the sibling-block wait)
    StageA a0 = LOADA(0);
    StageA a1 = LOADA(1);

    // rendezvous: relaxed poll, 16 pollers per flag, flag in its own 128B line
    if (tid == 0) {
        while (__hip_atomic_load(&cnt[t * 32], __ATOMIC_RELAXED, __HIP_MEMORY_SCOPE_AGENT) < 16)
            __builtin_amdgcn_s_sleep(16);
    }
    __syncthreads();                       // all threads ordered after the poll
    asm volatile("" ::: "memory");         // no compiler hoist of proto loads

    // hoist p_sq loads
    float psqv[2];
#pragma unroll
    for (int nf = 0; nf < 2; ++nf)
        psqv[nf] = p_sq[t * WAYS + wn * 32 + nf * 16 + fr];

    // prologue: B tiles 0,1; stage tile 0
    StageB b0 = LOADB(0);
    StageB b1 = LOADB(1);
    WRITE(0, a0, b0);
    asm volatile("s_waitcnt lgkmcnt(0)" ::: "memory");
    __builtin_amdgcn_s_barrier();

#pragma unroll
    for (int ks = 0; ks < NK; ++ks) {
        StageA na; StageB nb;
        if (ks < NK - 2) { na = LOADA(ks + 2); nb = LOADB(ks + 2); }
        COMPUTE(ks & 1);
        if (ks < NK - 1) WRITE((ks + 1) & 1, a1, b1);   // other buffer: no hazard
        a1 = na; b1 = nb;                               // full unroll -> regs
        asm volatile("s_waitcnt lgkmcnt(0)" ::: "memory");
        __builtin_amdgcn_s_barrier();                   // vmcnt NOT drained
    }

    // qsq: reduce over the 8 staging threads of each row (lanes ^1^2^4)
    qsq += __shfl_xor(qsq, 1, 64);
    qsq += __shfl_xor(qsq, 2, 64);
    qsq += __shfl_xor(qsq, 4, 64);
    if (sk8 == 0) qsq_s[srow] = qsq;
    __syncthreads();

    float* ob = out + ((size_t)(t * WQ + mt * 64 + wr * 16)) * WAYS;
#pragma unroll
    for (int r = 0; r < 4; ++r) {
        const int row = kg * 4 + r;                  // local row 0..15 in wave's group
        const float qv = qsq_s[wr * 16 + row];
#pragma unroll
        for (int nf = 0; nf < 2; ++nf) {
            ob[(size_t)row * WAYS + wn * 32 + nf * 16 + fr] =
                2.f * acc[nf][r] - qv - psqv[nf];
        }
    }
}

extern "C" void kernel_launch(void* const* d_in, const int* in_sizes, int n_in,
                              void* d_out, int out_size, void* d_ws, size_t ws_size,
                              hipStream_t stream) {
    const float* query   = (const float*)d_in[0];
    const float* support = (const float*)d_in[1];
    float* out = (float*)d_out;

    const size_t PROTO_BYTES = (size_t)T * WAYS * CDIM * sizeof(__bf16);   // 4 MB
    const size_t PSQ_BYTES   = (size_t)T * WAYS * sizeof(float);           // 8 KB
    __bf16* proto = (__bf16*)d_ws;
    float*  p_sq  = (float*)((char*)d_ws + PROTO_BYTES);
    int*    cnt   = (int*)((char*)d_ws + PROTO_BYTES + PSQ_BYTES);

    // zero the padded rendezvous flags every launch (graph-capturable)
    hipMemsetAsync(cnt, 0, T * 32 * sizeof(int), stream);

    hipLaunchKernelGGL(fused_kernel, dim3(T * 16), dim3(512), 0, stream,
                       query, support, out, proto, p_sq, cnt);
}

// Round 11
// 38.162 us; speedup vs baseline: 1.0754x; 1.0754x over previous
//
#include <hip/hip_runtime.h>
#include <hip/hip_bf16.h>

#define T 32
#define WAYS 64
#define SHOTS 8
#define CDIM 1024
#define WQ 1024
#define BK 128
#define NK 8    // K-steps of 128

typedef float f32x4 __attribute__((ext_vector_type(4)));
typedef __bf16 bf16x8 __attribute__((ext_vector_type(8)));

// Kernel 1: proto = mean over shots (stored bf16), p_sq = ||proto||^2 (fp32).
// XCD-chunked virtual block id: episode t is produced on XCD t>>2 -- the same
// XCD whose dist blocks consume it, so proto stays in that XCD's L2.
__global__ __launch_bounds__(256) void proto_kernel(const float* __restrict__ support,
                                                    __bf16* __restrict__ proto,
                                                    float* __restrict__ p_sq) {
    const int bx  = blockIdx.x;                  // 0..2047
    const int bid = (bx & 7) * 256 + (bx >> 3);  // XCD x owns bids [x*256,(x+1)*256)
    const int tid = threadIdx.x;
    const float* sp = support + (size_t)bid * (SHOTS * CDIM);
    float4 a = make_float4(0.f, 0.f, 0.f, 0.f);
#pragma unroll
    for (int s = 0; s < SHOTS; ++s) {
        const float4 v = *reinterpret_cast<const float4*>(sp + s * CDIM + tid * 4);
        a.x += v.x; a.y += v.y; a.z += v.z; a.w += v.w;
    }
    a.x *= 0.125f; a.y *= 0.125f; a.z *= 0.125f; a.w *= 0.125f;
    float ps = a.x * a.x + a.y * a.y + a.z * a.z + a.w * a.w;

    union { __bf16 h[4]; uint2 u; } pk;
    pk.h[0] = (__bf16)a.x; pk.h[1] = (__bf16)a.y; pk.h[2] = (__bf16)a.z; pk.h[3] = (__bf16)a.w;
    *reinterpret_cast<uint2*>(proto + (size_t)bid * CDIM + tid * 4) = pk.u;

#pragma unroll
    for (int m = 32; m >= 1; m >>= 1) ps += __shfl_down(ps, m, 64);
    __shared__ float red[4];
    const int wv = tid >> 6, ln = tid & 63;
    if (ln == 0) red[wv] = ps;
    __syncthreads();
    if (tid == 0) p_sq[bid] = red[0] + red[1] + red[2] + red[3];
}

// Kernel 2: 512 threads / 8 waves, block = 64 rows x 64 ways, BK=128.
// Wave = 16 rows x 32 ways. Double-buffered LDS, ONE raw barrier per K-step
// (lgkmcnt(0) only -- vmcnt never drained in-loop), depth-2 register prefetch,
// qsq fused into A staging, XOR-swizzled LDS, XCD-chunked block mapping.
// A staging is LINE-ALIGNED: each staging instr covers exactly one full 128B
// line per row (addr = p*128B + sk8*16B), not 4 partially-touched lines.
__global__ __launch_bounds__(512, 4) void dist_kernel(const float* __restrict__ query,
                                                      const __bf16* __restrict__ proto,
                                                      const float* __restrict__ p_sq,
                                                      float* __restrict__ out) {
    const int bx = blockIdx.x;
    const int vb = (bx & 7) * 64 + (bx >> 3);   // XCD-chunked: episode t -> XCD t>>2
    const int t   = vb >> 4;
    const int mt  = vb & 15;
    const int tid = threadIdx.x;
    const int lane = tid & 63;
    const int wid  = tid >> 6;
    const int wr   = wid >> 1;      // 0..3 : row group of 16
    const int wn   = wid & 1;       // 0..1 : way half of 32
    const int fr   = lane & 15;
    const int kg   = lane >> 4;

    __shared__ __bf16 As[2][64 * BK];
    __shared__ __bf16 Bs[2][64 * BK];
    __shared__ float qsq_s[64];

    // staging: thread -> (row 0..63, 4x one-128B-line chunks of A, 32B of B)
    const int srow = tid >> 3;
    const int sk8  = tid & 7;

    const float*  qbase = query + ((size_t)(t * WQ + mt * 64 + srow)) * CDIM;
    const __bf16* pbase = proto + ((size_t)(t * WAYS + srow)) * CDIM + sk8 * 16;

    struct Stage { f32x4 a[4]; uint4 b[2]; };

    auto LOAD = [&](int ks) -> Stage {
        Stage s;
        const float* ap = qbase + ks * BK;
#pragma unroll
        for (int p = 0; p < 4; ++p)   // p-th load: one contiguous 128B line per row
            s.a[p] = *reinterpret_cast<const f32x4*>(ap + p * 32 + sk8 * 4);
        const __bf16* bp = pbase + ks * BK;
        s.b[0] = *reinterpret_cast<const uint4*>(bp);
        s.b[1] = *reinterpret_cast<const uint4*>(bp + 8);
        return s;
    };

    float qsq = 0.f;

    auto WRITE = [&](int buf, const Stage& s) {
        const int swz = (srow & 7) << 4;
        char* ab = reinterpret_cast<char*>(As[buf]);
#pragma unroll
        for (int p = 0; p < 4; ++p) {
            qsq += s.a[p].x * s.a[p].x + s.a[p].y * s.a[p].y +
                   s.a[p].z * s.a[p].z + s.a[p].w * s.a[p].w;
            union { __bf16 h[4]; uint2 u; } pk;
            pk.h[0] = (__bf16)s.a[p].x; pk.h[1] = (__bf16)s.a[p].y;
            pk.h[2] = (__bf16)s.a[p].z; pk.h[3] = (__bf16)s.a[p].w;
            // thread holds k = p*32 + sk8*4 + {0..3}  ->  row byte 2k
            *reinterpret_cast<uint2*>(ab + ((srow * 256 + p * 64 + sk8 * 8) ^ swz)) = pk.u;
        }
        char* bb = reinterpret_cast<char*>(Bs[buf]);
        *reinterpret_cast<uint4*>(bb + ((srow * 256 + sk8 * 32) ^ swz))      = s.b[0];
        *reinterpret_cast<uint4*>(bb + ((srow * 256 + sk8 * 32 + 16) ^ swz)) = s.b[1];
    };

    f32x4 acc[2];
    acc[0] = (f32x4){0.f, 0.f, 0.f, 0.f};
    acc[1] = (f32x4){0.f, 0.f, 0.f, 0.f};

    auto COMPUTE = [&](int buf) {
        const char* ab = reinterpret_cast<const char*>(As[buf]);
        const char* bb = reinterpret_cast<const char*>(Bs[buf]);
#pragma unroll
        for (int ksub = 0; ksub < 4; ++ksub) {
            const int arow = wr * 16 + fr;
            const bf16x8 af = *reinterpret_cast<const bf16x8*>(
                ab + ((arow * 256 + ksub * 64 + kg * 16) ^ ((arow & 7) << 4)));
#pragma unroll
            for (int nf = 0; nf < 2; ++nf) {
                const int way = wn * 32 + nf * 16 + fr;
                const bf16x8 bf = *reinterpret_cast<const bf16x8*>(
                    bb + ((way * 256 + ksub * 64 + kg * 16) ^ ((way & 7) << 4)));
                acc[nf] = __builtin_amdgcn_mfma_f32_16x16x32_bf16(af, bf, acc[nf], 0, 0, 0);
            }
        }
    };

    // hoist p_sq loads (held across the K-loop)
    float psqv[2];
#pragma unroll
    for (int nf = 0; nf < 2; ++nf)
        psqv[nf] = p_sq[t * WAYS + wn * 32 + nf * 16 + fr];

    // prologue: stage tile 0, issue tile 1
    Stage s0 = LOAD(0);
    Stage sA = LOAD(1);
    WRITE(0, s0);
    asm volatile("s_waitcnt lgkmcnt(0)" ::: "memory");
    __builtin_amdgcn_s_barrier();

#pragma unroll
    for (int ks = 0; ks < NK; ++ks) {
        Stage nx;
        if (ks < NK - 2) nx = LOAD(ks + 2);          // issue early, consume next iter
        COMPUTE(ks & 1);
        if (ks < NK - 1) WRITE((ks + 1) & 1, sA);    // other buffer: no hazard
        sA = nx;                                     // full unroll -> stays in regs
        asm volatile("s_waitcnt lgkmcnt(0)" ::: "memory");
        __builtin_amdgcn_s_barrier();                // vmcnt NOT drained
    }

    // qsq: reduce over the 8 staging threads of each row (lanes ^1^2^4)
    qsq += __shfl_xor(qsq, 1, 64);
    qsq += __shfl_xor(qsq, 2, 64);
    qsq += __shfl_xor(qsq, 4, 64);
    if (sk8 == 0) qsq_s[srow] = qsq;
    __syncthreads();

    float* ob = out + ((size_t)(t * WQ + mt * 64 + wr * 16)) * WAYS;
#pragma unroll
    for (int r = 0; r < 4; ++r) {
        const int row = kg * 4 + r;                  // local row 0..15 in wave's group
        const float qv = qsq_s[wr * 16 + row];
#pragma unroll
        for (int nf = 0; nf < 2; ++nf) {
            ob[(size_t)row * WAYS + wn * 32 + nf * 16 + fr] =
                2.f * acc[nf][r] - qv - psqv[nf];
        }
    }
}

extern "C" void kernel_launch(void* const* d_in, const int* in_sizes, int n_in,
                              void* d_out, int out_size, void* d_ws, size_t ws_size,
                              hipStream_t stream) {
    const float* query   = (const float*)d_in[0];
    const float* support = (const float*)d_in[1];
    float* out = (float*)d_out;

    __bf16* proto = (__bf16*)d_ws;                                   // 4 MB
    float*  p_sq  = (float*)((char*)d_ws + (size_t)T * WAYS * CDIM * sizeof(__bf16));

    hipLaunchKernelGGL(proto_kernel, dim3(T * WAYS), dim3(256), 0, stream,
                       support, proto, p_sq);
    hipLaunchKernelGGL(dist_kernel, dim3(T * 16), dim3(512), 0, stream,
                       query, proto, p_sq, out);
}